// Round 1
// baseline (247.280 us; speedup 1.0000x reference)
//
#include <hip/hip_runtime.h>

#define B_    1024
#define T_    2048
#define SEAS_ 24
#define IS_   24
#define OS_   48
#define C_    6
#define W_    1977   // T - OS - IS + 1
#define SFW_  2096   // seas_full width: 24 + 1 + 2047 + 24
#define LDN_  2047   // number of log-diff entries

__device__ __forceinline__ float frcp(float x) { return __builtin_amdgcn_rcpf(x); }

// ---------------- Kernel 1: the sequential ES scan, one thread per series ----------------
__global__ __launch_bounds__(64) void scan_kernel(
    const float* __restrict__ x, const float* __restrict__ lev_sms,
    const float* __restrict__ seas_sms, const float* __restrict__ seasonalities,
    const int* __restrict__ idxs,
    float* __restrict__ levs_out, float* __restrict__ seas_out,
    float* __restrict__ deseas_ws, float* __restrict__ ld_ws)
{
    int b = blockIdx.x * 64 + threadIdx.x;
    const float* xr   = x        + (size_t)b * T_;
    float* levr       = levs_out + (size_t)b * T_;
    float* seasr      = seas_out + (size_t)b * SFW_;
    float* desr       = deseas_ws + (size_t)b * T_;

    int id = idxs[b];
    float lev_a  = 1.0f / (1.0f + __expf(-lev_sms[id]));
    float seas_b = 1.0f / (1.0f + __expf(-seas_sms[id]));
    float oma = 1.0f - lev_a, omb = 1.0f - seas_b;

    float s[SEAS_];
    #pragma unroll
    for (int j = 0; j < SEAS_; ++j) {
        s[j] = __expf(seasonalities[id * SEAS_ + j]);
        seasr[j] = s[j];
    }
    seasr[SEAS_] = s[0];                     // seas_full[24] = seas0[0]

    float x0  = xr[0];
    float lev = x0 * frcp(s[0]);             // lev0
    levr[0] = lev;
    desr[0] = lev;                           // deseas[b,0] = x0/seas0[0] = lev0
    float prev_log = __logf(lev);

    // t = 1..2047 : 85 unrolled bodies of 24 steps (t=1..2040) + 7-step tail.
    // pos = t % 24 is compile-time inside the unrolled bodies -> s[] stays in VGPRs.
    for (int body = 0; body < 85; ++body) {
        int t0 = 1 + body * 24;
        float xv[24];
        #pragma unroll
        for (int j = 0; j < 24; ++j) xv[j] = xr[t0 + j];
        #pragma unroll
        for (int j = 0; j < 24; ++j) {
            const int pos = (j + 1 < 24) ? (j + 1) : 0;
            float xi    = xv[j];
            float ratio = xi * frcp(s[pos]);                       // = deseas[b,t]
            float nl    = __builtin_fmaf(oma, lev, lev_a * ratio); // new_lev
            float cl    = __logf(nl);
            float ld    = cl - prev_log;                           // log(new/prev)
            float ns    = __builtin_fmaf(omb, s[pos], seas_b * (xi * frcp(nl)));
            s[pos] = ns;
            int t = t0 + j;
            levr[t]          = nl;
            seasr[SEAS_ + t] = ns;        // seas_full[24 + t] = new_seas(t)
            desr[t]          = ratio;
            ld_ws[(size_t)(t - 1) * B_ + b] = ld;   // transposed: coalesced across lanes
            lev = nl;
            prev_log = cl;
        }
    }
    {
        const int t0 = 2041;
        #pragma unroll
        for (int j = 0; j < 7; ++j) {
            const int pos = j + 1;        // 2041 % 24 = 1
            float xi    = xr[t0 + j];
            float ratio = xi * frcp(s[pos]);
            float nl    = __builtin_fmaf(oma, lev, lev_a * ratio);
            float cl    = __logf(nl);
            float ld    = cl - prev_log;
            float ns    = __builtin_fmaf(omb, s[pos], seas_b * (xi * frcp(nl)));
            s[pos] = ns;
            int t = t0 + j;
            levr[t]          = nl;
            seasr[SEAS_ + t] = ns;
            desr[t]          = ratio;
            ld_ws[(size_t)(t - 1) * B_ + b] = ld;
            lev = nl;
            prev_log = cl;
        }
    }
    // seas_full tail: seas_full[2072+j] = new_seas(2024+j) = s[(8+j)%24]  (2024%24==8)
    #pragma unroll
    for (int j = 0; j < SEAS_; ++j) {
        seasr[2072 + j] = s[(8 + j) % 24];
    }
}

// ---------------- Kernel 2: window materialization (243 MB, memory-bound) ----------------
// out[w][b][k]: k<24 -> deseas[b, w+k] / levs[b, w+23]; k>=24 -> info_cat[b, k-24].
// One float2 per thread: pair index j in 0..14 (12 deseas pairs, 3 info pairs).
__global__ __launch_bounds__(256) void win_kernel(
    const float* __restrict__ deseas, const float* __restrict__ levs,
    const float* __restrict__ info_cat, float2* __restrict__ out)
{
    int w  = blockIdx.y;
    int e2 = blockIdx.x * 256 + threadIdx.x;   // 0..15359 == B*15 exactly
    int b  = e2 / 15;
    int j  = e2 - b * 15;
    float2 v;
    if (j < 12) {
        float inv = frcp(levs[b * T_ + w + 23]);
        int t = w + 2 * j;
        v.x = deseas[b * T_ + t]     * inv;
        v.y = deseas[b * T_ + t + 1] * inv;
    } else {
        int c = 2 * (j - 12);
        v.x = info_cat[b * C_ + c];
        v.y = info_cat[b * C_ + c + 1];
    }
    out[(size_t)w * 15360 + e2] = v;
}

// ---------------- Kernel 3: mean over batch of (ld[i+1]-ld[i])^2 ----------------
__global__ __launch_bounds__(256) void msld_kernel(
    const float* __restrict__ ld_ws, float* __restrict__ out)
{
    int i = blockIdx.x;                        // 0..2045
    const float* r0 = ld_ws + (size_t)i * B_;
    const float* r1 = r0 + B_;
    float ssum = 0.0f;
    #pragma unroll
    for (int r = 0; r < 4; ++r) {
        int b = threadIdx.x + 256 * r;
        float d = r1[b] - r0[b];
        ssum = __builtin_fmaf(d, d, ssum);
    }
    #pragma unroll
    for (int off = 32; off > 0; off >>= 1) ssum += __shfl_down(ssum, off);
    __shared__ float partial[4];
    int wid = threadIdx.x >> 6;
    if ((threadIdx.x & 63) == 0) partial[wid] = ssum;
    __syncthreads();
    if (threadIdx.x == 0)
        out[i] = (partial[0] + partial[1] + partial[2] + partial[3]) * (1.0f / 1024.0f);
}

extern "C" void kernel_launch(void* const* d_in, const int* in_sizes, int n_in,
                              void* d_out, int out_size, void* d_ws, size_t ws_size,
                              hipStream_t stream)
{
    const float* train    = (const float*)d_in[0];
    // d_in[1] = val, d_in[2] = test : unused by the reference outputs
    const float* info_cat = (const float*)d_in[3];
    const float* lev_sms  = (const float*)d_in[4];
    const float* seas_sms = (const float*)d_in[5];
    const float* seasonal = (const float*)d_in[6];
    const int*   idxs     = (const int*)d_in[7];

    float* out      = (float*)d_out;
    float* out_ib   = out;                               // W*B*30 = 60,733,440
    float* out_levs = out + (size_t)W_ * B_ * 30;        // B*T    =  2,097,152
    float* out_seas = out_levs + (size_t)B_ * T_;        // B*2096 =  2,146,304
    float* out_msld = out_seas + (size_t)B_ * SFW_;      // 2046

    float* ws        = (float*)d_ws;
    float* deseas_ws = ws;                               // B*T floats   (8.4 MB)
    float* ld_ws     = ws + (size_t)B_ * T_;             // 2047*B floats (8.4 MB)

    scan_kernel<<<B_ / 64, 64, 0, stream>>>(train, lev_sms, seas_sms, seasonal, idxs,
                                            out_levs, out_seas, deseas_ws, ld_ws);

    dim3 g2(60, W_);   // 60*256 = 15360 = B*15 pairs per w
    win_kernel<<<g2, 256, 0, stream>>>(deseas_ws, out_levs, info_cat, (float2*)out_ib);

    msld_kernel<<<LDN_ - 1, 256, 0, stream>>>(ld_ws, out_msld);
}

// Round 4
// 161.486 us; speedup vs baseline: 1.5313x; 1.5313x over previous
//
#include <hip/hip_runtime.h>

#define B_    1024
#define T_    2048
#define SEAS_ 24
#define C_    6
#define W_    1977   // T - OS - IS + 1
#define SFW_  2096   // seas_full width

typedef float vf2 __attribute__((ext_vector_type(2)));

__device__ __forceinline__ float frcp(float x) { return __builtin_amdgcn_rcpf(x); }

// ---------------- Kernel 1: minimal sequential ES scan, fully coalesced stores ----------
// ws layout: levT[t][b]  (2048 rows)  : lev values, row t = lev at time t (row 0 = lev0)
//            nsT[r][b]   (2047 rows)  : new_seas at step t stored at row r = t-1
__global__ __launch_bounds__(64) void scan_kernel(
    const float* __restrict__ x, const float* __restrict__ lev_sms,
    const float* __restrict__ seas_sms, const float* __restrict__ seasonalities,
    const int* __restrict__ idxs,
    float* __restrict__ levT, float* __restrict__ nsT)
{
    int b = blockIdx.x * 64 + threadIdx.x;
    const float* xr = x + (size_t)b * T_;

    int id = idxs[b];
    float lev_a  = 1.0f / (1.0f + __expf(-lev_sms[id]));
    float seas_b = 1.0f / (1.0f + __expf(-seas_sms[id]));
    float oma = 1.0f - lev_a, omb = 1.0f - seas_b;

    float s[SEAS_];
    #pragma unroll
    for (int j = 0; j < SEAS_; ++j) s[j] = __expf(seasonalities[id * SEAS_ + j]);

    float lev = xr[0] * frcp(s[0]);
    levT[b] = lev;                                   // row 0

    float xv[24], xn[24];
    #pragma unroll
    for (int j = 0; j < 24; ++j) xv[j] = xr[1 + j];

    for (int body = 0; body < 85; ++body) {
        int t0 = 1 + body * 24;
        if (body < 84) {                              // prefetch next body
            #pragma unroll
            for (int j = 0; j < 24; ++j) xn[j] = xr[t0 + 24 + j];
        } else {
            #pragma unroll
            for (int j = 0; j < 7; ++j) xn[j] = xr[2041 + j];
        }
        #pragma unroll
        for (int j = 0; j < 24; ++j) {
            const int pos = (j + 1 < 24) ? (j + 1) : 0;
            float xi    = xv[j];
            float ratio = xi * frcp(s[pos]);
            float nl    = __builtin_fmaf(oma, lev, lev_a * ratio);
            float ns    = __builtin_fmaf(omb, s[pos], seas_b * (xi * frcp(nl)));
            s[pos] = ns;
            int t = t0 + j;
            levT[(size_t)t * B_ + b]      = nl;      // coalesced
            nsT[(size_t)(t - 1) * B_ + b] = ns;      // coalesced
            lev = nl;
        }
        #pragma unroll
        for (int j = 0; j < 24; ++j) xv[j] = xn[j];
    }
    // tail t = 2041..2047 (pos = 1..7)
    #pragma unroll
    for (int j = 0; j < 7; ++j) {
        const int pos = j + 1;
        float xi    = xv[j];
        float ratio = xi * frcp(s[pos]);
        float nl    = __builtin_fmaf(oma, lev, lev_a * ratio);
        float ns    = __builtin_fmaf(omb, s[pos], seas_b * (xi * frcp(nl)));
        s[pos] = ns;
        int t = 2041 + j;
        levT[(size_t)t * B_ + b]      = nl;
        nsT[(size_t)(t - 1) * B_ + b] = ns;
        lev = nl;
    }
}

// ---------------- seas head: out_seas[b][u], u<25 (seas0 values) ----------------
__global__ __launch_bounds__(256) void seas_head_kernel(
    const float* __restrict__ seasonalities, const int* __restrict__ idxs,
    float* __restrict__ out_seas)
{
    int idx = blockIdx.x * 256 + threadIdx.x;        // 0..25599
    if (idx >= B_ * 25) return;
    int b = idx / 25, u = idx - b * 25;
    int id = idxs[b];
    out_seas[(size_t)b * SFW_ + u] = __expf(seasonalities[id * SEAS_ + (u < 24 ? u : 0)]);
}

// ---------------- transpose levT[t][b] -> out_levs[b][t] ----------------
__global__ __launch_bounds__(256) void transposeL_kernel(
    const float* __restrict__ levT, float* __restrict__ out)
{
    __shared__ float tile[32][33];
    int bt = blockIdx.y * 32;                        // t tile
    int bb = blockIdx.x * 32;                        // b tile
    int tx = threadIdx.x, ty = threadIdx.y;          // (32, 8)
    #pragma unroll
    for (int r = 0; r < 32; r += 8)
        tile[ty + r][tx] = levT[(size_t)(bt + ty + r) * B_ + bb + tx];
    __syncthreads();
    #pragma unroll
    for (int r = 0; r < 32; r += 8)
        out[(size_t)(bb + ty + r) * T_ + bt + tx] = tile[tx][ty + r];
}

// ---------------- transpose nsT -> out_seas[b][u] for u in [25, 2096) ----------------
// mapping: u in [25,2072): row = u-25 ;  u in [2072,2096): row = u-49 (seasonal tail repeat)
__global__ __launch_bounds__(256) void transposeS_kernel(
    const float* __restrict__ nsT, float* __restrict__ out_seas)
{
    __shared__ float tile[32][33];
    int bu = blockIdx.y * 32;
    int bb = blockIdx.x * 32;
    int tx = threadIdx.x, ty = threadIdx.y;
    #pragma unroll
    for (int r = 0; r < 32; r += 8) {
        int u = bu + ty + r;
        if (u >= 25 && u < SFW_) {
            int rr = u - 25 - (u >= 2072 ? 24 : 0);
            tile[ty + r][tx] = nsT[(size_t)rr * B_ + bb + tx];
        }
    }
    __syncthreads();
    #pragma unroll
    for (int r = 0; r < 32; r += 8) {
        int u = bu + tx;
        if (u >= 25 && u < SFW_)
            out_seas[(size_t)(bb + ty + r) * SFW_ + u] = tile[tx][ty + r];
    }
}

// ---------------- window materialization (243 MB, write-bound) ----------------
// out[w][b][k]: k<24 -> (x[b][w+k]/seas[b][w+k]) / levs[b][w+23]; k>=24 -> info_cat[b][k-24]
__global__ __launch_bounds__(256) void win_kernel(
    const float* __restrict__ x, const float* __restrict__ levs,
    const float* __restrict__ seasF, const float* __restrict__ info_cat,
    vf2* __restrict__ out)
{
    int w  = blockIdx.y;
    int e2 = blockIdx.x * 256 + threadIdx.x;         // 0..15359 == B*15
    int b  = e2 / 15;
    int j  = e2 - b * 15;
    vf2 v;
    if (j < 12) {
        float inv = frcp(levs[b * T_ + w + 23]);
        int t = w + 2 * j;
        float sa = seasF[b * SFW_ + t];
        float sb = seasF[b * SFW_ + t + 1];
        v.x = x[b * T_ + t]     * frcp(sa) * inv;
        v.y = x[b * T_ + t + 1] * frcp(sb) * inv;
    } else {
        int c = 2 * (j - 12);
        v.x = info_cat[b * C_ + c];
        v.y = info_cat[b * C_ + c + 1];
    }
    __builtin_nontemporal_store(v, &out[(size_t)w * 15360 + e2]);
}

// ---------------- msld: mean_b (logL[i+2] - 2 logL[i+1] + logL[i])^2 ----------------
__global__ __launch_bounds__(256) void msld_kernel(
    const float* __restrict__ levT, float* __restrict__ out)
{
    int i = blockIdx.x;                              // 0..2045
    const float* r0 = levT + (size_t)i * B_;
    float ssum = 0.0f;
    #pragma unroll
    for (int r = 0; r < 4; ++r) {
        int b = threadIdx.x + 256 * r;
        float l0 = __logf(r0[b]);
        float l1 = __logf(r0[b + B_]);
        float l2 = __logf(r0[b + 2 * B_]);
        float d  = l2 - 2.0f * l1 + l0;
        ssum = __builtin_fmaf(d, d, ssum);
    }
    #pragma unroll
    for (int off = 32; off > 0; off >>= 1) ssum += __shfl_down(ssum, off);
    __shared__ float partial[4];
    int wid = threadIdx.x >> 6;
    if ((threadIdx.x & 63) == 0) partial[wid] = ssum;
    __syncthreads();
    if (threadIdx.x == 0)
        out[i] = (partial[0] + partial[1] + partial[2] + partial[3]) * (1.0f / 1024.0f);
}

extern "C" void kernel_launch(void* const* d_in, const int* in_sizes, int n_in,
                              void* d_out, int out_size, void* d_ws, size_t ws_size,
                              hipStream_t stream)
{
    const float* train    = (const float*)d_in[0];
    const float* info_cat = (const float*)d_in[3];
    const float* lev_sms  = (const float*)d_in[4];
    const float* seas_sms = (const float*)d_in[5];
    const float* seasonal = (const float*)d_in[6];
    const int*   idxs     = (const int*)d_in[7];

    float* out      = (float*)d_out;
    float* out_ib   = out;                               // W*B*30
    float* out_levs = out + (size_t)W_ * B_ * 30;        // B*2048
    float* out_seas = out_levs + (size_t)B_ * T_;        // B*2096
    float* out_msld = out_seas + (size_t)B_ * SFW_;      // 2046

    float* ws   = (float*)d_ws;
    float* levT = ws;                                    // 2048*1024 floats
    float* nsT  = ws + (size_t)T_ * B_;                  // 2047*1024 floats

    scan_kernel<<<B_ / 64, 64, 0, stream>>>(train, lev_sms, seas_sms, seasonal, idxs,
                                            levT, nsT);

    seas_head_kernel<<<(B_ * 25 + 255) / 256, 256, 0, stream>>>(seasonal, idxs, out_seas);

    msld_kernel<<<2046, 256, 0, stream>>>(levT, out_msld);

    dim3 tb(32, 8);
    transposeL_kernel<<<dim3(B_ / 32, T_ / 32), tb, 0, stream>>>(levT, out_levs);
    transposeS_kernel<<<dim3(B_ / 32, (SFW_ + 31) / 32), tb, 0, stream>>>(nsT, out_seas);

    dim3 g2(60, W_);
    win_kernel<<<g2, 256, 0, stream>>>(train, out_levs, out_seas, info_cat, (vf2*)out_ib);
}